// Round 4
// baseline (274.930 us; speedup 1.0000x reference)
//
#include <hip/hip_runtime.h>
#include <hip/hip_bf16.h>

// Problem constants
#define BB   4
#define FF   9
#define MPP  100
#define PP   12000
#define CC   64
#define NYY  400
#define NXO  4
#define NPIL (BB * PP)              // 48000
#define NWIN (BB * NYY * NXO)       // 6400 pooling windows

// ws layout (byte offsets) — bins/feat2 offsets identical to verified layout
#define WS_CNT    0                        // 6400 * 4  (window occupancy counts)
#define WS_BINS   36352                    // 6400*100 u16 pillar ids
#define WS_FEAT2  (WS_BINS + 1280000)      // 48000*64 bf16 (16B-aligned)

typedef __attribute__((ext_vector_type(8)))  short short8;   // 8 bf16 = 4 VGPRs
typedef __attribute__((ext_vector_type(16))) float float16;  // MFMA 32x32 acc
typedef __attribute__((ext_vector_type(4)))  int int4v;

__device__ __forceinline__ short f2bf(float v) {
    __hip_bfloat16 h = __float2bfloat16(v);
    short s; __builtin_memcpy(&s, &h, 2); return s;
}
__device__ __forceinline__ float bf2f(unsigned short u) {
    return __int_as_float(((int)u) << 16);
}
// order-preserving fp32 <-> int key (self-inverse XOR form)
__device__ __forceinline__ int fkey(float v) {
    int b = __float_as_int(v);
    return b >= 0 ? b : (b ^ 0x7fffffff);
}
__device__ __forceinline__ float kinv(int k) {
    return __int_as_float(k >= 0 ? k : (k ^ 0x7fffffff));
}
// pack two fp32 -> one dword of 2 bf16 (lo = first arg)
__device__ __forceinline__ unsigned pack2(float lo, float hi) {
    unsigned a = (unsigned short)f2bf(lo);
    unsigned b = (unsigned short)f2bf(hi);
    return a | (b << 16);
}
// v_permlane32_swap_b32: a' = {a.lo-half, b.lo-half}; b' = {a.hi-half, b.hi-half}
__device__ __forceinline__ void pls(unsigned &a, unsigned &b) {
    asm volatile("v_permlane32_swap_b32 %0, %1" : "+v"(a), "+v"(b));
}
__device__ __forceinline__ short8 mk8(unsigned a, unsigned b, unsigned c) {
    int4v t; t[0] = (int)a; t[1] = (int)b; t[2] = (int)c; t[3] = 0;
    short8 r; __builtin_memcpy(&r, &t, 16); return r;
}

// 9 fully-coalesced NT dword loads: lanes = 64 consecutive pillars (256 B/req).
// Per-lane loff carries batch offset (handles blocks straddling the batch seam).
#define LOAD9(g, mp_) do { \
    const float* bp_ = xq + (size_t)(mp_) * PP; \
    g##0 = __builtin_nontemporal_load(bp_ + loff); \
    g##1 = __builtin_nontemporal_load(bp_ + 1 * FS + loff); \
    g##2 = __builtin_nontemporal_load(bp_ + 2 * FS + loff); \
    g##3 = __builtin_nontemporal_load(bp_ + 3 * FS + loff); \
    g##4 = __builtin_nontemporal_load(bp_ + 4 * FS + loff); \
    g##5 = __builtin_nontemporal_load(bp_ + 5 * FS + loff); \
    g##6 = __builtin_nontemporal_load(bp_ + 6 * FS + loff); \
    g##7 = __builtin_nontemporal_load(bp_ + 7 * FS + loff); \
    g##8 = __builtin_nontemporal_load(bp_ + 8 * FS + loff); } while (0)

// One point: build BOTH 32-pillar-tile B-fragments via 3 permlane32_swaps.
// Slot map (matches w1pb): lane<32 slots0-3 = f0-3 (own pillar);
// lane>=32 slots8-12 = f4-8 (partner pillar via swap). Slots 4-7/13-15 are
// don't-cares (w1pb zeros). 4 MFMAs, 64 fmax.
#define STEPP(g) do { \
    unsigned p01 = pack2(g##0, g##1), p23 = pack2(g##2, g##3); \
    unsigned p45 = pack2(g##4, g##5), p67 = pack2(g##6, g##7); \
    unsigned p8z = pack2(g##8, 0.f);  unsigned zz = 0u; \
    pls(p01, p45); pls(p23, p67); pls(zz, p8z); \
    const short8 fr0 = mk8(p01, p23, zz); \
    const short8 fr1 = mk8(p45, p67, p8z); \
    const float16 zA = __builtin_amdgcn_mfma_f32_32x32x16_bf16(af0, fr0, (float16)0.f, 0, 0, 0); \
    const float16 zB = __builtin_amdgcn_mfma_f32_32x32x16_bf16(af1, fr0, (float16)0.f, 0, 0, 0); \
    const float16 zC = __builtin_amdgcn_mfma_f32_32x32x16_bf16(af0, fr1, (float16)0.f, 0, 0, 0); \
    const float16 zD = __builtin_amdgcn_mfma_f32_32x32x16_bf16(af1, fr1, (float16)0.f, 0, 0, 0); \
    _Pragma("unroll") \
    for (int r = 0; r < 16; ++r) { \
        vmx00[r] = fmaxf(vmx00[r], zA[r]); \
        vmx10[r] = fmaxf(vmx10[r], zB[r]); \
        vmx01[r] = fmaxf(vmx01[r], zC[r]); \
        vmx11[r] = fmaxf(vmx11[r], zD[r]); \
    } } while (0)

// Block = 256 threads (4 waves), 64 pillars. Wave wv owns mp-quarter
// [25wv, 25wv+25) for ALL 64 pillars. In-block weight prep (LDS).
// Cross-wave merge: LDS atomicMax on order-int keys (red int[64ch][64p], 16KB).
// Stage2: 4 waves x (d-tile, p-tile), K=64 MFMA chain -> relu -> s2f (overlays
// red) -> dense coalesced bf16 feat2 store. Binning: 1 atomicAdd per pillar.
__global__ __launch_bounds__(256, 3) void pillar_kernel(
    const float* __restrict__ x, const int* __restrict__ coords,
    const float* __restrict__ w1, const float* __restrict__ b1,
    const float* __restrict__ g1, const float* __restrict__ be1,
    const float* __restrict__ m1, const float* __restrict__ v1,
    const float* __restrict__ w2, const float* __restrict__ b2,
    const float* __restrict__ g2, const float* __restrict__ be2,
    const float* __restrict__ m2, const float* __restrict__ v2,
    char* __restrict__ ws, int* __restrict__ cnt)
{
    __shared__ char  arena[16896];        // red int[64][64] THEN s2f fp32[64][66]
    __shared__ short featbT[64 * 72];     // bf16 feat [p][c], stride 72 (16B-aligned)
    __shared__ short w1pb_s[64 * 16];     // s1-folded w1, k-slot mapped
    __shared__ short w2pb_s[64 * 80];     // s2-folded w2, stride 80 (16B-aligned rows)
    __shared__ float bias1_s[64];
    __shared__ float bias2_s[64];

    int*   red = (int*)arena;
    float* s2f = (float*)arena;

    unsigned short* bins  = (unsigned short*)(ws + WS_BINS);
    short*          feat2 = (short*)(ws + WS_FEAT2);

    const int t    = threadIdx.x;
    const int lane = t & 63;
    const int wv   = t >> 6;          // 0..3 = mp quarter
    const int half = lane >> 5;       // k-group
    const int pcol = lane & 31;       // pillar column within tile / A row (m)
    const int v0   = blockIdx.x * 64; // 64 pillars per block (may straddle batch)

    // init reduction buffer (4096 ints, 16/thread), barrier before any atomicMax
    #pragma unroll
    for (int i = 0; i < 16; ++i) red[i * 256 + t] = (int)0x80000000;

    // binning: 1 atomicAdd per pillar (48k total across grid)
    if (t < 64) {
        const int* c4 = coords + (size_t)(v0 + t) * 4;
        const int w = (c4[0] * NYY + c4[2]) * NXO + c4[3] / 100;
        const int slot = atomicAdd(&cnt[w], 1);
        bins[w * 100 + slot] = (unsigned short)(v0 + t);
    }

    // in-block weight prep (k-slot map: s<4 -> f=s ; 8<=s<13 -> f=s-4)
    if (t < 64) {
        const float s1 = g1[t] * rsqrtf(v1[t] + 1e-3f);
        bias1_s[t] = s1 * b1[t] + (be1[t] - m1[t] * s1);
        #pragma unroll
        for (int s = 0; s < 16; ++s) {
            const int f = (s < 4) ? s : ((s >= 8 && s < 13) ? s - 4 : -1);
            w1pb_s[t * 16 + s] = (f >= 0) ? f2bf(s1 * w1[t * 9 + f]) : (short)0;
        }
        const float s2 = g2[t] * rsqrtf(v2[t] + 1e-3f);
        bias2_s[t] = s2 * b2[t] + (be2[t] - m2[t] * s2);
    }
    #pragma unroll
    for (int i0 = 0; i0 < 16; ++i0) {      // 16*256 == 64*64
        const int i = i0 * 256 + t;
        const int d = i >> 6;
        const float s2d = g2[d] * rsqrtf(v2[d] + 1e-3f);
        w2pb_s[d * 80 + (i & 63)] = f2bf(s2d * w2[i]);
    }
    __syncthreads();

    // A fragments: w1' rows (k-slot mapped) for channels pcol and pcol+32
    const short8 af0 = *(const short8*)(w1pb_s + pcol * 16 + half * 8);
    const short8 af1 = *(const short8*)(w1pb_s + (pcol + 32) * 16 + half * 8);

    float16 vmx00, vmx10, vmx01, vmx11;
    #pragma unroll
    for (int r = 0; r < 16; ++r) {
        vmx00[r] = -3.0e38f; vmx10[r] = -3.0e38f;
        vmx01[r] = -3.0e38f; vmx11[r] = -3.0e38f;
    }

    // per-lane pillar: pid = v0 + lane; per-lane batch (handles seam blocks)
    const size_t FS = (size_t)MPP * PP;    // feature-plane stride (floats)
    const int pid = v0 + lane;
    const int bl  = pid / PP;
    const int loff = bl * (int)(FF * FS) + (pid - bl * PP);  // < 2^25, fits int
    const float* xq = x + (size_t)(wv * 25) * PP;            // wave's mp base

    // 25 points: 12 pairs + 1 tail; 18 NT loads in flight per pair
    float a_0, a_1, a_2, a_3, a_4, a_5, a_6, a_7, a_8;
    float b_0, b_1, b_2, b_3, b_4, b_5, b_6, b_7, b_8;
    for (int it = 0; it < 12; ++it) {
        LOAD9(a_, 2 * it);
        LOAD9(b_, 2 * it + 1);
        STEPP(a_);
        STEPP(b_);
    }
    LOAD9(a_, 24);
    STEPP(a_);

    // merge across 4 mp-quarter waves: LDS atomicMax on ordered-int keys
    // D layout: col(n)=lane&31, row(chl)=(r&3)+8*(r>>2)+4*(lane>>5)
    #pragma unroll
    for (int r = 0; r < 16; ++r) {
        const int chl = (r & 3) + 8 * (r >> 2) + 4 * half;
        atomicMax(&red[chl * 64 + pcol],             fkey(vmx00[r]));
        atomicMax(&red[(chl + 32) * 64 + pcol],      fkey(vmx10[r]));
        atomicMax(&red[chl * 64 + 32 + pcol],        fkey(vmx01[r]));
        atomicMax(&red[(chl + 32) * 64 + 32 + pcol], fkey(vmx11[r]));
    }
    __syncthreads();

    // feat = relu(max + bias1) -> bf16, transposed [p][c]
    {
        const int p  = t & 63;
        const int cg = t >> 6;      // 0..3, 16 channels each
        #pragma unroll
        for (int j = 0; j < 16; ++j) {
            const int c = cg * 16 + j;
            const float m = kinv(red[c * 64 + p]);
            featbT[p * 72 + c] = f2bf(fmaxf(0.f, m + bias1_s[c]));
        }
    }
    __syncthreads();

    // Stage2: wave wv -> (d-tile = wv&1, p-tile = wv>>1), K=64 in 4 chunks.
    // s2f overlays red (red fully consumed above, barrier passed).
    {
        const int dt = wv & 1, pt = wv >> 1;
        const short* wrow = &w2pb_s[(dt * 32 + pcol) * 80 + half * 8];
        const short8 wa0 = *(const short8*)(wrow +  0);
        const short8 wa1 = *(const short8*)(wrow + 16);
        const short8 wa2 = *(const short8*)(wrow + 32);
        const short8 wa3 = *(const short8*)(wrow + 48);
        const short* frow = &featbT[(pt * 32 + pcol) * 72 + half * 8];
        const short8 fb0 = *(const short8*)(frow +  0);
        const short8 fb1 = *(const short8*)(frow + 16);
        const short8 fb2 = *(const short8*)(frow + 32);
        const short8 fb3 = *(const short8*)(frow + 48);

        float16 acc = (float16)0.f;
        acc = __builtin_amdgcn_mfma_f32_32x32x16_bf16(wa0, fb0, acc, 0, 0, 0);
        acc = __builtin_amdgcn_mfma_f32_32x32x16_bf16(wa1, fb1, acc, 0, 0, 0);
        acc = __builtin_amdgcn_mfma_f32_32x32x16_bf16(wa2, fb2, acc, 0, 0, 0);
        acc = __builtin_amdgcn_mfma_f32_32x32x16_bf16(wa3, fb3, acc, 0, 0, 0);

        #pragma unroll
        for (int r = 0; r < 16; ++r) {
            const int d = dt * 32 + (r & 3) + 8 * (r >> 2) + 4 * half;
            s2f[(pt * 32 + pcol) * 66 + d] = fmaxf(0.f, acc[r] + bias2_s[d]);
        }
    }
    __syncthreads();

    // dense coalesced bf16 store: feat2[(v0+p)*64 + d], 32 B/thread
    {
        const int p  = t >> 2;
        const int d0 = (t & 3) * 16;
        short8 o0, o1;
        #pragma unroll
        for (int j = 0; j < 8; ++j) {
            o0[j] = f2bf(s2f[p * 66 + d0 + j]);
            o1[j] = f2bf(s2f[p * 66 + d0 + 8 + j]);
        }
        *(short8*)(feat2 + (size_t)(v0 + p) * 64 + d0)     = o0;
        *(short8*)(feat2 + (size_t)(v0 + p) * 64 + d0 + 8) = o1;
    }
}

// One WAVE per window (grid 1600 blocks x 4 windows/block). Lane: dg = lane&3
// (16 d's), cc = lane>>2 (16 parallel bin-walkers, stride 16) -> <=7 trips.
// Cross-lane max-reduce via shfl_xor over bits 2..5, lanes cc==0 store.
__global__ __launch_bounds__(256) void gather_kernel(
    const float* __restrict__ g2, const float* __restrict__ b2,
    const float* __restrict__ be2, const float* __restrict__ m2,
    const float* __restrict__ v2,
    const char* __restrict__ ws, const int* __restrict__ cnt,
    float* __restrict__ out)
{
    const unsigned short* bins  = (const unsigned short*)(ws + WS_BINS);
    const unsigned short* feat2 = (const unsigned short*)(ws + WS_FEAT2);

    const int t    = threadIdx.x;
    const int lane = t & 63;
    const int wv   = t >> 6;
    const int w    = blockIdx.x * 4 + wv;     // < 6400
    const int dg   = lane & 3;                // d-quarter
    const int cc   = lane >> 2;               // bin-walker index 0..15
    const int k    = cnt[w];

    float m[16];
    #pragma unroll
    for (int j = 0; j < 16; ++j) {
        const int d = dg * 16 + j;
        const float s2 = g2[d] * rsqrtf(v2[d] + 1e-3f);
        const float bias2d = s2 * b2[d] + (be2[d] - m2[d] * s2);
        const float zv = fmaxf(0.f, bias2d);
        m[j] = (k >= 100) ? 0.f : zv;         // post-ReLU vals >= 0, so 0 is safe
    }

    const unsigned short* brow = bins + (size_t)w * 100;
    for (int i = cc; i < k; i += 16) {
        const int pid = brow[i];
        const unsigned short* row = feat2 + (size_t)pid * 64 + dg * 16;
        const short8 a0 = *(const short8*)(row);
        const short8 a1 = *(const short8*)(row + 8);
        #pragma unroll
        for (int j = 0; j < 8; ++j) {
            m[j]     = fmaxf(m[j],     bf2f((unsigned short)a0[j]));
            m[j + 8] = fmaxf(m[j + 8], bf2f((unsigned short)a1[j]));
        }
    }

    // reduce across the 16 walkers sharing this dg (xor on lane bits 2..5)
    #pragma unroll
    for (int off = 4; off < 64; off <<= 1) {
        #pragma unroll
        for (int j = 0; j < 16; ++j)
            m[j] = fmaxf(m[j], __shfl_xor(m[j], off, 64));
    }

    if (cc == 0) {
        const int b   = w / (NYY * NXO);
        const int rem = w - b * (NYY * NXO);
        const int y   = rem >> 2;
        const int xo  = rem & 3;
        #pragma unroll
        for (int j = 0; j < 16; ++j) {
            const int d = dg * 16 + j;
            out[(((size_t)b * CC + d) * NYY + y) * NXO + xo] = m[j];
        }
    }
}

extern "C" void kernel_launch(void* const* d_in, const int* in_sizes, int n_in,
                              void* d_out, int out_size, void* d_ws, size_t ws_size,
                              hipStream_t stream) {
    const float* x   = (const float*)d_in[0];
    const int*   cds = (const int*)d_in[1];
    const float* w1  = (const float*)d_in[2];
    const float* b1  = (const float*)d_in[3];
    const float* g1  = (const float*)d_in[4];
    const float* be1 = (const float*)d_in[5];
    const float* m1  = (const float*)d_in[6];
    const float* v1  = (const float*)d_in[7];
    const float* w2  = (const float*)d_in[8];
    const float* b2  = (const float*)d_in[9];
    const float* g2  = (const float*)d_in[10];
    const float* be2 = (const float*)d_in[11];
    const float* m2  = (const float*)d_in[12];
    const float* v2  = (const float*)d_in[13];

    char* ws = (char*)d_ws;
    int*  cnt = (int*)(ws + WS_CNT);

    // zero only the 25.6 KB window counters (ws re-poisoned 0xAA each launch)
    hipMemsetAsync(cnt, 0, (size_t)NWIN * 4, stream);

    pillar_kernel<<<NPIL / 64, 256, 0, stream>>>(x, cds,
                                                 w1, b1, g1, be1, m1, v1,
                                                 w2, b2, g2, be2, m2, v2,
                                                 ws, cnt);

    gather_kernel<<<NWIN / 4, 256, 0, stream>>>(g2, b2, be2, m2, v2,
                                                ws, cnt, (float*)d_out);
}